// Round 5
// baseline (645.189 us; speedup 1.0000x reference)
//
#include <hip/hip_runtime.h>
#include <math.h>

#define BB 8
#define SS 512
#define DD 768
#define HH 12
#define DKK 64
#define NTOK (BB*SS)                       // 4096
#define NELEM (25165824ull)                // B*H*S*S
#define NPROJ 3145728                      // 4096*768 elements per projection
#define WSZ   589824                       // 768*768
#define SCALEQ 0.03608439182435161f        // 1/sqrt(768)

typedef unsigned short u16;
typedef short short8 __attribute__((ext_vector_type(8)));
typedef float f32x4 __attribute__((ext_vector_type(4)));
typedef unsigned short u16x4 __attribute__((ext_vector_type(4)));

#define MFMA16 __builtin_amdgcn_mfma_f32_16x16x32_bf16

__device__ inline u16 f32_to_bf16(float f) {
    unsigned int u = __float_as_uint(f);
    unsigned int r = u + 0x7fffu + ((u >> 16) & 1u);   // RNE
    return (u16)(r >> 16);
}
__device__ inline float bf16_to_f32(u16 h) {
    return __uint_as_float(((unsigned int)h) << 16);
}

// async global->LDS, 16B per lane; LDS dst = wave-uniform base + lane*16
__device__ __forceinline__ void gld16(const u16* g, u16* l) {
    __builtin_amdgcn_global_load_lds(
        (const __attribute__((address_space(1))) unsigned int*)g,
        (__attribute__((address_space(3))) unsigned int*)l, 16, 0, 0);
}

// ---------------------------------------------------------------------------
// Transpose + split-cast the 6 weight matrices; block (0,0,0) zeroes loss.
// ---------------------------------------------------------------------------
__global__ __launch_bounds__(256)
void cast_wT(const float* __restrict__ W0, const float* __restrict__ W1,
             const float* __restrict__ W2, const float* __restrict__ W3,
             const float* __restrict__ W4, const float* __restrict__ W5,
             u16* __restrict__ WTh, u16* __restrict__ WTl,
             float* __restrict__ lossp)
{
    __shared__ float tile[32][33];
    if (blockIdx.x == 0 && blockIdx.y == 0 && blockIdx.z == 0 && threadIdx.x == 0)
        *lossp = 0.0f;
    const int z = blockIdx.z;
    const float* W;
    switch (z) {
        case 0: W = W0; break; case 1: W = W1; break; case 2: W = W2; break;
        case 3: W = W3; break; case 4: W = W4; break; default: W = W5; break;
    }
    u16* th = WTh + (size_t)z * WSZ;
    u16* tl = WTl + (size_t)z * WSZ;
    const int t = threadIdx.x;
    const int k0 = blockIdx.y * 32, n0 = blockIdx.x * 32;
    const int rr = t >> 3, c0 = (t & 7) * 4;

    float4 v = *(const float4*)(W + (size_t)(k0 + rr) * DD + n0 + c0);
    tile[rr][c0 + 0] = v.x; tile[rr][c0 + 1] = v.y;
    tile[rr][c0 + 2] = v.z; tile[rr][c0 + 3] = v.w;
    __syncthreads();

    u16x4 hw, lw;
#pragma unroll
    for (int i = 0; i < 4; ++i) {
        float f = tile[c0 + i][rr];
        u16 hi = f32_to_bf16(f);
        hw[i] = hi;
        lw[i] = f32_to_bf16(f - bf16_to_f32(hi));
    }
    size_t o = (size_t)(n0 + rr) * DD + k0 + c0;
    *(u16x4*)&th[o] = hw;
    *(u16x4*)&tl[o] = lw;
}

// ---------------------------------------------------------------------------
// Split-cast X (query,key): f32 -> hi/lo bf16 flat buffers.
// ---------------------------------------------------------------------------
__global__ __launch_bounds__(256)
void cast_X(const float* __restrict__ query, const float* __restrict__ key,
            u16* __restrict__ Xh, u16* __restrict__ Xl)
{
    const float* src = blockIdx.y ? key : query;
    u16* dh = Xh + (size_t)blockIdx.y * NPROJ;
    u16* dl = Xl + (size_t)blockIdx.y * NPROJ;
    size_t i0 = ((size_t)blockIdx.x * 256 + threadIdx.x) * 8;
    float f[8];
    *(float4*)&f[0] = *(const float4*)(src + i0);
    *(float4*)&f[4] = *(const float4*)(src + i0 + 4);
    short8 h, l;
#pragma unroll
    for (int i = 0; i < 8; ++i) {
        u16 hi = f32_to_bf16(f[i]);
        h[i] = (short)hi;
        l[i] = (short)f32_to_bf16(f[i] - bf16_to_f32(hi));
    }
    *(short8*)&dh[i0] = h;
    *(short8*)&dl[i0] = l;
}

// ---------------------------------------------------------------------------
// Projection GEMM v2: operand-swapped MFMA (lane acc = 4 consecutive n)
// -> packed u16x4 stores. z<4: 3-term bf16x3 hi/lo out; z>=4: hi-only 1-term.
// 128x128 tile, BK=32, 256 threads (4 waves), global_load_lds staging.
// ---------------------------------------------------------------------------
__global__ __launch_bounds__(256)
void proj_gemm_gld(const u16* __restrict__ Xh, const u16* __restrict__ Xl,
                   const u16* __restrict__ WTh, const u16* __restrict__ WTl,
                   const float* __restrict__ b0, const float* __restrict__ b1,
                   const float* __restrict__ b2, const float* __restrict__ b3,
                   const float* __restrict__ b4, const float* __restrict__ b5,
                   u16* __restrict__ Ph, u16* __restrict__ Pl)
{
    __shared__ alignas(16) u16 Ash[128][32];   // unpadded: gld16 requires contiguity
    __shared__ alignas(16) u16 Asl[128][32];
    __shared__ alignas(16) u16 Bsh[128][32];
    __shared__ alignas(16) u16 Bsl[128][32];

    const int z = blockIdx.z;
    const float* bias;
    switch (z) {
        case 0: bias = b0; break; case 1: bias = b1; break; case 2: bias = b2; break;
        case 3: bias = b3; break; case 4: bias = b4; break; default: bias = b5; break;
    }
    const float scl = (z & 1) ? 1.0f : SCALEQ;
    const u16* Ah_g = Xh + (size_t)(z & 1) * NPROJ;
    const u16* Al_g = Xl + (size_t)(z & 1) * NPROJ;
    const u16* WThz = WTh + (size_t)z * WSZ;
    const u16* WTlz = WTl + (size_t)z * WSZ;
    u16* Ch = Ph + (size_t)z * NPROJ;
    u16* Cl = Pl + (size_t)z * NPROJ;
    const bool wlo = (z < 4);

    const int t = threadIdx.x;
    const int w = t >> 6, l = t & 63, quad = l >> 4, ln = l & 15;
    const int m0 = blockIdx.y * 128, n0 = blockIdx.x * 128;
    const int wm = (w & 1) * 64, wn = (w >> 1) * 64;

    const int srow = w * 16 + (l >> 2);
    const int scol = (l & 3) * 8;
    const u16* gAh = Ah_g + (size_t)(m0 + srow) * DD + scol;
    const u16* gAl = Al_g + (size_t)(m0 + srow) * DD + scol;
    const u16* gBh = WThz + (size_t)(n0 + srow) * DD + scol;
    const u16* gBl = WTlz + (size_t)(n0 + srow) * DD + scol;
    u16* lAh0 = &Ash[w * 16][0];      u16* lAh1 = &Ash[w * 16 + 64][0];
    u16* lAl0 = &Asl[w * 16][0];      u16* lAl1 = &Asl[w * 16 + 64][0];
    u16* lBh0 = &Bsh[w * 16][0];      u16* lBh1 = &Bsh[w * 16 + 64][0];
    u16* lBl0 = &Bsl[w * 16][0];      u16* lBl1 = &Bsl[w * 16 + 64][0];
    const size_t rstep = (size_t)64 * DD;

    f32x4 acc[4][4];   // acc[mt][nt]; lane holds n = wn+nt*16+quad*4+reg, m = wm+mt*16+ln
#pragma unroll
    for (int i = 0; i < 4; ++i)
#pragma unroll
        for (int jj = 0; jj < 4; ++jj) acc[i][jj] = (f32x4){0.f, 0.f, 0.f, 0.f};

    for (int k0 = 0; k0 < DD; k0 += 32) {
        gld16(gAh + k0, lAh0);  gld16(gAh + k0 + rstep, lAh1);
        gld16(gBh + k0, lBh0);  gld16(gBh + k0 + rstep, lBh1);
        if (wlo) {
            gld16(gAl + k0, lAl0);  gld16(gAl + k0 + rstep, lAl1);
            gld16(gBl + k0, lBl0);  gld16(gBl + k0 + rstep, lBl1);
        }
        __syncthreads();

        short8 afh[4], afl[4], bfh[4], bfl[4];
#pragma unroll
        for (int mt = 0; mt < 4; ++mt)
            afh[mt] = *(const short8*)&Ash[wm + mt * 16 + ln][quad * 8];
#pragma unroll
        for (int nt = 0; nt < 4; ++nt)
            bfh[nt] = *(const short8*)&Bsh[wn + nt * 16 + ln][quad * 8];
        if (wlo) {
#pragma unroll
            for (int mt = 0; mt < 4; ++mt)
                afl[mt] = *(const short8*)&Asl[wm + mt * 16 + ln][quad * 8];
#pragma unroll
            for (int nt = 0; nt < 4; ++nt)
                bfl[nt] = *(const short8*)&Bsl[wn + nt * 16 + ln][quad * 8];
        }
        // operand-swapped: first operand indexes D's row dim (= n), second = m
#pragma unroll
        for (int mt = 0; mt < 4; ++mt)
#pragma unroll
            for (int nt = 0; nt < 4; ++nt) {
                acc[mt][nt] = MFMA16(bfh[nt], afh[mt], acc[mt][nt], 0, 0, 0);
                if (wlo) {
                    acc[mt][nt] = MFMA16(bfl[nt], afh[mt], acc[mt][nt], 0, 0, 0);
                    acc[mt][nt] = MFMA16(bfh[nt], afl[mt], acc[mt][nt], 0, 0, 0);
                }
            }
        __syncthreads();
    }

    // epilogue: lane stores 4 consecutive n as u16x4
#pragma unroll
    for (int nt = 0; nt < 4; ++nt) {
        const int nb4 = n0 + wn + nt * 16 + quad * 4;
        float4 bias4 = *(const float4*)(bias + nb4);
        float bv[4] = {bias4.x, bias4.y, bias4.z, bias4.w};
#pragma unroll
        for (int mt = 0; mt < 4; ++mt) {
            const int m = m0 + wm + mt * 16 + ln;
            u16x4 hv, lv;
#pragma unroll
            for (int reg = 0; reg < 4; ++reg) {
                float c = (acc[mt][nt][reg] + bv[reg]) * scl;
                u16 hi = f32_to_bf16(c);
                hv[reg] = hi;
                lv[reg] = f32_to_bf16(c - bf16_to_f32(hi));
            }
            size_t o = (size_t)m * DD + nb4;
            *(u16x4*)&Ch[o] = hv;
            if (wlo) *(u16x4*)&Cl[o] = lv;
        }
    }
}

// ---------------------------------------------------------------------------
// Fallback projection GEMM (round-2 style, f32 A staged in-kernel).
// ---------------------------------------------------------------------------
__global__ __launch_bounds__(256)
void proj_gemm_mfma(const float* __restrict__ query, const float* __restrict__ key,
                    const u16* __restrict__ WTh, const u16* __restrict__ WTl,
                    const float* __restrict__ b0, const float* __restrict__ b1,
                    const float* __restrict__ b2, const float* __restrict__ b3,
                    const float* __restrict__ b4, const float* __restrict__ b5,
                    u16* __restrict__ Ph, u16* __restrict__ Pl)
{
    __shared__ alignas(16) u16 Ash[128][40];
    __shared__ alignas(16) u16 Asl[128][40];
    __shared__ alignas(16) u16 Bsh[128][40];
    __shared__ alignas(16) u16 Bsl[128][40];

    const int z = blockIdx.z;
    const float* X = (z & 1) ? key : query;
    const float* bias;
    switch (z) {
        case 0: bias = b0; break; case 1: bias = b1; break; case 2: bias = b2; break;
        case 3: bias = b3; break; case 4: bias = b4; break; default: bias = b5; break;
    }
    const float scl = (z & 1) ? 1.0f : SCALEQ;
    const u16* WThz = WTh + (size_t)z * WSZ;
    const u16* WTlz = WTl + (size_t)z * WSZ;
    u16* Ch = Ph + (size_t)z * NPROJ;
    u16* Cl = Pl + (size_t)z * NPROJ;
    const bool wlo = (z < 4);

    const int t = threadIdx.x;
    const int w = t >> 6, l = t & 63, quad = l >> 4, ln = l & 15;
    const int m0 = blockIdx.y * 128, n0 = blockIdx.x * 128;
    const int wm = (w & 1) * 64, wn = (w >> 1) * 64;

    const int arow = t >> 1, akoff = (t & 1) * 16;
    const int brow = t >> 1, bkoff = (t & 1) * 16;

    f32x4 acc[4][4];
#pragma unroll
    for (int i = 0; i < 4; ++i)
#pragma unroll
        for (int jj = 0; jj < 4; ++jj) acc[i][jj] = (f32x4){0.f, 0.f, 0.f, 0.f};

    for (int k0 = 0; k0 < DD; k0 += 32) {
        {
            const float* asrc = X + (size_t)(m0 + arow) * DD + k0 + akoff;
            float fa[16];
            *(float4*)&fa[0]  = *(const float4*)(asrc + 0);
            *(float4*)&fa[4]  = *(const float4*)(asrc + 4);
            *(float4*)&fa[8]  = *(const float4*)(asrc + 8);
            *(float4*)&fa[12] = *(const float4*)(asrc + 12);
            short8 h0, h1, l0, l1;
#pragma unroll
            for (int i = 0; i < 8; ++i) {
                u16 hi = f32_to_bf16(fa[i]);
                h0[i] = (short)hi;
                l0[i] = (short)f32_to_bf16(fa[i] - bf16_to_f32(hi));
                u16 hi2 = f32_to_bf16(fa[8 + i]);
                h1[i] = (short)hi2;
                l1[i] = (short)f32_to_bf16(fa[8 + i] - bf16_to_f32(hi2));
            }
            *(short8*)&Ash[arow][akoff]     = h0;
            *(short8*)&Ash[arow][akoff + 8] = h1;
            *(short8*)&Asl[arow][akoff]     = l0;
            *(short8*)&Asl[arow][akoff + 8] = l1;
        }
        {
            const u16* bhp = WThz + (size_t)(n0 + brow) * DD + k0 + bkoff;
            const u16* blp = WTlz + (size_t)(n0 + brow) * DD + k0 + bkoff;
            *(uint4*)&Bsh[brow][bkoff]     = *(const uint4*)(bhp);
            *(uint4*)&Bsh[brow][bkoff + 8] = *(const uint4*)(bhp + 8);
            *(uint4*)&Bsl[brow][bkoff]     = *(const uint4*)(blp);
            *(uint4*)&Bsl[brow][bkoff + 8] = *(const uint4*)(blp + 8);
        }
        __syncthreads();

        short8 afh[4], afl[4], bfh[4], bfl[4];
#pragma unroll
        for (int mt = 0; mt < 4; ++mt) {
            afh[mt] = *(const short8*)&Ash[wm + mt * 16 + ln][quad * 8];
            afl[mt] = *(const short8*)&Asl[wm + mt * 16 + ln][quad * 8];
        }
#pragma unroll
        for (int nt = 0; nt < 4; ++nt) {
            bfh[nt] = *(const short8*)&Bsh[wn + nt * 16 + ln][quad * 8];
            bfl[nt] = *(const short8*)&Bsl[wn + nt * 16 + ln][quad * 8];
        }
#pragma unroll
        for (int mt = 0; mt < 4; ++mt)
#pragma unroll
            for (int nt = 0; nt < 4; ++nt) {
                acc[mt][nt] = MFMA16(bfh[nt], afh[mt], acc[mt][nt], 0, 0, 0);
                acc[mt][nt] = MFMA16(bfl[nt], afh[mt], acc[mt][nt], 0, 0, 0);
                acc[mt][nt] = MFMA16(bfh[nt], afl[mt], acc[mt][nt], 0, 0, 0);
            }
        __syncthreads();
    }

#pragma unroll
    for (int nt = 0; nt < 4; ++nt) {
        const int nb4 = n0 + wn + nt * 16 + quad * 4;
        float4 bias4 = *(const float4*)(bias + nb4);
        float bv[4] = {bias4.x, bias4.y, bias4.z, bias4.w};
#pragma unroll
        for (int mt = 0; mt < 4; ++mt) {
            const int m = m0 + wm + mt * 16 + ln;
            u16x4 hv, lv;
#pragma unroll
            for (int reg = 0; reg < 4; ++reg) {
                float c = (acc[mt][nt][reg] + bv[reg]) * scl;
                u16 hi = f32_to_bf16(c);
                hv[reg] = hi;
                lv[reg] = f32_to_bf16(c - bf16_to_f32(hi));
            }
            size_t o = (size_t)m * DD + nb4;
            *(u16x4*)&Ch[o] = hv;
            if (wlo) *(u16x4*)&Cl[o] = lv;
        }
    }
}

// ---------------------------------------------------------------------------
// Attention v7: r4 structure (fused L+R phase, 3 barriers, M-frag prefetch)
// + BCE computed in the tail from p IN REGISTERS (never re-read outp).
// span loads issued right after barrier 2 -> HBM latency hides under
// phase-2 MFMA + softmax M. Loss: width-64 shfl reduce + 1 atomic per wave
// (lred/extra barrier deleted). r4's separate bce_loss kernel (103 us,
// dependent 200 MB re-read) is deleted entirely.
// ---------------------------------------------------------------------------
#define CPITCH 532
__global__ __launch_bounds__(512, 4)
void attn_mfma(const u16* __restrict__ Ph, const u16* __restrict__ Pl,
               const float* __restrict__ mask, const float* __restrict__ span,
               float* __restrict__ outp, float* __restrict__ lossp)
{
    __shared__ float curbL[16][CPITCH];
    __shared__ float curbR[16][CPITCH];

    const int t = threadIdx.x;
    const int blk = blockIdx.x;
    const int qt = blk & 31;
    const int bh = blk >> 5;
    const int b = bh / HH, h = bh % HH;
    const int w = t >> 6, l = t & 63, quad = l >> 4, ln = l & 15;
    const int r = t >> 5, j = t & 31;
    const int qrow = qt * 16 + r;
    const int bb = 33 * (j >> 1) + 16 * (j & 1);   // layout-B base (16 consecutive)
    const int cB = j * 16;                         // first column owned in layout B

    float smbr[16];

    const size_t qoff = (size_t)(b * SS + qt * 16 + ln) * DD + h * DKK + quad * 8;
    const size_t koff = (size_t)(b * SS + w * 16 + ln) * DD + h * DKK + quad * 8;

    const u16* QhL = Ph + 0 * (size_t)NPROJ;  const u16* QlL = Pl + 0 * (size_t)NPROJ;
    const u16* KhL = Ph + 1 * (size_t)NPROJ;  const u16* KlL = Pl + 1 * (size_t)NPROJ;
    const u16* QhR = Ph + 2 * (size_t)NPROJ;  const u16* QlR = Pl + 2 * (size_t)NPROJ;
    const u16* KhR = Ph + 3 * (size_t)NPROJ;  const u16* KlR = Pl + 3 * (size_t)NPROJ;
    const u16* QhM = Ph + 4 * (size_t)NPROJ;
    const u16* KhM = Ph + 5 * (size_t)NPROJ;

    // ---------------- Phase 1: L+R scores (fused, one barrier region) ------
    {
        short8 aLh0 = *(const short8*)(QhL + qoff);
        short8 aLh1 = *(const short8*)(QhL + qoff + 32);
        short8 aLl0 = *(const short8*)(QlL + qoff);
        short8 aLl1 = *(const short8*)(QlL + qoff + 32);
        short8 aRh0 = *(const short8*)(QhR + qoff);
        short8 aRh1 = *(const short8*)(QhR + qoff + 32);
        short8 aRl0 = *(const short8*)(QlR + qoff);
        short8 aRl1 = *(const short8*)(QlR + qoff + 32);
#pragma unroll
        for (int kc = 0; kc < 4; ++kc) {
            const size_t off = koff + (size_t)kc * (128 * DD);
            const int cb = kc * 128 + w * 16 + ln;
            const int ci = cb + (cb >> 5);
            {
                short8 bh0 = *(const short8*)(KhL + off);
                short8 bh1 = *(const short8*)(KhL + off + 32);
                short8 bl0 = *(const short8*)(KlL + off);
                short8 bl1 = *(const short8*)(KlL + off + 32);
                f32x4 acc = (f32x4){0.f, 0.f, 0.f, 0.f};
                acc = MFMA16(aLh0, bh0, acc, 0, 0, 0);
                acc = MFMA16(aLh1, bh1, acc, 0, 0, 0);
                acc = MFMA16(aLh0, bl0, acc, 0, 0, 0);
                acc = MFMA16(aLh1, bl1, acc, 0, 0, 0);
                acc = MFMA16(aLl0, bh0, acc, 0, 0, 0);
                acc = MFMA16(aLl1, bh1, acc, 0, 0, 0);
#pragma unroll
                for (int reg = 0; reg < 4; ++reg)
                    curbL[quad * 4 + reg][ci] = acc[reg];
            }
            {
                short8 bh0 = *(const short8*)(KhR + off);
                short8 bh1 = *(const short8*)(KhR + off + 32);
                short8 bl0 = *(const short8*)(KlR + off);
                short8 bl1 = *(const short8*)(KlR + off + 32);
                f32x4 acc = (f32x4){0.f, 0.f, 0.f, 0.f};
                acc = MFMA16(aRh0, bh0, acc, 0, 0, 0);
                acc = MFMA16(aRh1, bh1, acc, 0, 0, 0);
                acc = MFMA16(aRh0, bl0, acc, 0, 0, 0);
                acc = MFMA16(aRh1, bl1, acc, 0, 0, 0);
                acc = MFMA16(aRl0, bh0, acc, 0, 0, 0);
                acc = MFMA16(aRl1, bh1, acc, 0, 0, 0);
#pragma unroll
                for (int reg = 0; reg < 4; ++reg)
                    curbR[quad * 4 + reg][ci] = acc[reg];
            }
        }
    }
    __syncthreads();    // barrier 1: L+R scores visible

    // Prefetch stage M fragments NOW -- they fly under the softmax VALU.
    short8 aMh0 = *(const short8*)(QhM + qoff);
    short8 aMh1 = *(const short8*)(QhM + qoff + 32);
    short8 km0[4], km1[4];
#pragma unroll
    for (int kc = 0; kc < 4; ++kc) {
        const size_t off = koff + (size_t)kc * (128 * DD);
        km0[kc] = *(const short8*)(KhM + off);
        km1[kc] = *(const short8*)(KhM + off + 32);
    }

    // ---------------- Softmax L (layout B, r2-verified) ----------------
    {
        float e[16];
        float mx = -3.0e38f;
#pragma unroll
        for (int u = 0; u < 16; ++u) {
            float v = curbL[r][bb + u];
            e[u] = v;
            if (cB + u <= qrow && v > mx) mx = v;
        }
#pragma unroll
        for (int off = 16; off >= 1; off >>= 1) mx = fmaxf(mx, __shfl_xor(mx, off));
        float s = 0.0f;
#pragma unroll
        for (int u = 0; u < 16; ++u) {
            float ev = (cB + u <= qrow) ? __expf(e[u] - mx) : 0.0f;
            s += ev;
            e[u] = s;
        }
        float incl = s;
#pragma unroll
        for (int off = 1; off < 32; off <<= 1) {
            float ww = __shfl_up(incl, off, 32);
            if (j >= off) incl += ww;
        }
        float offset = incl - s;
        float inv = 1.0f / __shfl(incl, 31, 32);
#pragma unroll
        for (int u = 0; u < 16; ++u) smbr[u] = (offset + e[u]) * inv;
    }

    // ---------------- Softmax R (layout B, r2-verified) ----------------
    {
        float e[16];
        float mx = -3.0e38f;
#pragma unroll
        for (int u = 0; u < 16; ++u) {
            float v = curbR[r][bb + u];
            e[u] = v;
            if (cB + u >= qrow && v > mx) mx = v;
        }
#pragma unroll
        for (int off = 16; off >= 1; off >>= 1) mx = fmaxf(mx, __shfl_xor(mx, off));
        float s = 0.0f;
#pragma unroll
        for (int u = 15; u >= 0; --u) {
            float ev = (cB + u >= qrow) ? __expf(e[u] - mx) : 0.0f;
            s += ev;
            e[u] = s;
        }
        float incl = s;
#pragma unroll
        for (int off = 1; off < 32; off <<= 1) {
            float ww = __shfl_down(incl, off, 32);
            if (j + off < 32) incl += ww;
        }
        float offset = incl - s;
        float inv = 1.0f / __shfl(incl, 0, 32);
#pragma unroll
        for (int u = 0; u < 16; ++u) smbr[u] *= (offset + e[u]) * inv;

        // transpose smbr B -> A through curbL (each thread overwrites only
        // positions it alone read in softmax L -> no pre-barrier)
#pragma unroll
        for (int u = 0; u < 16; ++u) curbL[r][bb + u] = smbr[u];
    }
    __syncthreads();    // barrier 2: transpose visible; curbR free for M

    // span prefetch: issued NOW so HBM latency hides under phase-2 MFMA +
    // softmax M; consumed only in the BCE tail.
    const float* sprow = span + (((size_t)(h * BB + b) * SS + qrow)) * SS;
    float sp[16];
#pragma unroll
    for (int u = 0; u < 16; ++u) sp[u] = sprow[u * 32 + j];

    // smbr in layout A
#pragma unroll
    for (int u = 0; u < 16; ++u) smbr[u] = curbL[r][u * 33 + j];

    // ---------------- Phase 2: M scores (prefetched frags) ----------------
#pragma unroll
    for (int kc = 0; kc < 4; ++kc) {
        const int cb = kc * 128 + w * 16 + ln;
        const int ci = cb + (cb >> 5);
        f32x4 acc = (f32x4){0.f, 0.f, 0.f, 0.f};
        acc = MFMA16(aMh0, km0[kc], acc, 0, 0, 0);
        acc = MFMA16(aMh1, km1[kc], acc, 0, 0, 0);
#pragma unroll
        for (int reg = 0; reg < 4; ++reg)
            curbR[quad * 4 + reg][ci] = acc[reg];
    }
    __syncthreads();    // barrier 3: M scores visible

    // ---------------- Softmax M + p store + in-register BCE ---------------
    {
        float mv  = mask[b * SS + qrow];
        float rmq = (mv == -10000.0f) ? 1.0e9f : mv;
        float vb[16];
        float mx = -3.0e38f;
#pragma unroll
        for (int u = 0; u < 16; ++u) {
            int c = u * 32 + j;
            float mk  = mask[b * SS + c];
            float rmk = (mk == -10000.0f) ? 1.0e9f : mk;
            float v = (curbR[r][u * 33 + j] - rmq - rmk) * smbr[u];
            vb[u] = v;
            mx = fmaxf(mx, v);
        }
#pragma unroll
        for (int off = 16; off >= 1; off >>= 1) mx = fmaxf(mx, __shfl_xor(mx, off));
        float sum = 0.0f;
#pragma unroll
        for (int u = 0; u < 16; ++u) {
            float ev = __expf(vb[u] - mx);
            vb[u] = ev; sum += ev;
        }
#pragma unroll
        for (int off = 16; off >= 1; off >>= 1) sum += __shfl_xor(sum, off);
        float inv = 1.0f / sum;

        float* orow = outp + (((size_t)(b * HH + h) * SS + qrow)) * SS;
        float lsum = 0.0f;
#pragma unroll
        for (int u = 0; u < 16; ++u) {
            float p = vb[u] * inv;
            orow[u * 32 + j] = p;
            lsum += __logf(1.0f + __expf(-p)) + (1.0f - sp[u]) * p;
        }
        // width-64 wave reduce + 1 atomic per wave (no LDS, no extra barrier)
#pragma unroll
        for (int off = 32; off >= 1; off >>= 1) lsum += __shfl_xor(lsum, off);
        if (l == 0) atomicAdd(lossp, lsum * (float)(1.0 / 25165824.0));
    }
}

extern "C" void kernel_launch(void* const* d_in, const int* in_sizes, int n_in,
                              void* d_out, int out_size, void* d_ws, size_t ws_size,
                              hipStream_t stream)
{
    const float* query = (const float*)d_in[0];
    const float* key_t = (const float*)d_in[1];
    const float* mask  = (const float*)d_in[2];
    const float* span  = (const float*)d_in[3];
    const float* Wql = (const float*)d_in[4];  const float* bql = (const float*)d_in[5];
    const float* Wkl = (const float*)d_in[6];  const float* bkl = (const float*)d_in[7];
    const float* Wqr = (const float*)d_in[8];  const float* bqr = (const float*)d_in[9];
    const float* Wkr = (const float*)d_in[10]; const float* bkr = (const float*)d_in[11];
    const float* Wq  = (const float*)d_in[12]; const float* bq  = (const float*)d_in[13];
    const float* Wk  = (const float*)d_in[14]; const float* bk  = (const float*)d_in[15];

    float* out = (float*)d_out;
    float* lossp = out + NELEM;

    // ws layout (u16): WTh[6W] WTl[6W] Ph[6P] Pl[4P] | Xh[2P] Xl[2P] (big-ws only)
    u16* ws16 = (u16*)d_ws;
    u16* WTh = ws16;
    u16* WTl = WTh + (size_t)6 * WSZ;
    u16* Ph  = WTl + (size_t)6 * WSZ;
    u16* Pl  = Ph + (size_t)6 * NPROJ;
    u16* Xh  = Pl + (size_t)4 * NPROJ;
    u16* Xl  = Xh + (size_t)2 * NPROJ;
    const size_t need_big = ((size_t)12 * WSZ + (size_t)14 * NPROJ) * 2;  // 102.24 MB
    const bool bigws = ws_size >= need_big;

    cast_wT<<<dim3(24, 24, 6), dim3(256), 0, stream>>>(
        Wql, Wkl, Wqr, Wkr, Wq, Wk, WTh, WTl, lossp);

    if (bigws) {
        cast_X<<<dim3(1536, 2), dim3(256), 0, stream>>>(query, key_t, Xh, Xl);
        proj_gemm_gld<<<dim3(DD / 128, NTOK / 128, 6), dim3(256), 0, stream>>>(
            Xh, Xl, WTh, WTl, bql, bkl, bqr, bkr, bq, bk, Ph, Pl);
    } else {
        proj_gemm_mfma<<<dim3(DD / 128, NTOK / 128, 6), dim3(256), 0, stream>>>(
            query, key_t, WTh, WTl, bql, bkl, bqr, bkr, bq, bk, Ph, Pl);
    }

    attn_mfma<<<dim3(96 * 32), dim3(512), 0, stream>>>(
        Ph, Pl, mask, span, out, lossp);
}

// Round 6
// 457.897 us; speedup vs baseline: 1.4090x; 1.4090x over previous
//
#include <hip/hip_runtime.h>
#include <math.h>

#define BB 8
#define SS 512
#define DD 768
#define HH 12
#define DKK 64
#define NTOK (BB*SS)                       // 4096
#define NELEM (25165824ull)                // B*H*S*S
#define NPROJ 3145728                      // 4096*768 elements per projection
#define WSZ   589824                       // 768*768
#define SCALEQ 0.03608439182435161f        // 1/sqrt(768)

typedef unsigned short u16;
typedef short short8 __attribute__((ext_vector_type(8)));
typedef float f32x4 __attribute__((ext_vector_type(4)));
typedef unsigned short u16x4 __attribute__((ext_vector_type(4)));

#define MFMA16 __builtin_amdgcn_mfma_f32_16x16x32_bf16

__device__ inline u16 f32_to_bf16(float f) {
    unsigned int u = __float_as_uint(f);
    unsigned int r = u + 0x7fffu + ((u >> 16) & 1u);   // RNE
    return (u16)(r >> 16);
}
__device__ inline float bf16_to_f32(u16 h) {
    return __uint_as_float(((unsigned int)h) << 16);
}

// async global->LDS, 16B per lane; LDS dst = wave-uniform base + lane*16
__device__ __forceinline__ void gld16(const u16* g, u16* l) {
    __builtin_amdgcn_global_load_lds(
        (const __attribute__((address_space(1))) unsigned int*)g,
        (__attribute__((address_space(3))) unsigned int*)l, 16, 0, 0);
}

// ---------------------------------------------------------------------------
// Transpose + split-cast the 6 weight matrices; block (0,0,0) zeroes loss.
// ---------------------------------------------------------------------------
__global__ __launch_bounds__(256)
void cast_wT(const float* __restrict__ W0, const float* __restrict__ W1,
             const float* __restrict__ W2, const float* __restrict__ W3,
             const float* __restrict__ W4, const float* __restrict__ W5,
             u16* __restrict__ WTh, u16* __restrict__ WTl,
             float* __restrict__ lossp)
{
    __shared__ float tile[32][33];
    if (blockIdx.x == 0 && blockIdx.y == 0 && blockIdx.z == 0 && threadIdx.x == 0)
        *lossp = 0.0f;
    const int z = blockIdx.z;
    const float* W;
    switch (z) {
        case 0: W = W0; break; case 1: W = W1; break; case 2: W = W2; break;
        case 3: W = W3; break; case 4: W = W4; break; default: W = W5; break;
    }
    u16* th = WTh + (size_t)z * WSZ;
    u16* tl = WTl + (size_t)z * WSZ;
    const int t = threadIdx.x;
    const int k0 = blockIdx.y * 32, n0 = blockIdx.x * 32;
    const int rr = t >> 3, c0 = (t & 7) * 4;

    float4 v = *(const float4*)(W + (size_t)(k0 + rr) * DD + n0 + c0);
    tile[rr][c0 + 0] = v.x; tile[rr][c0 + 1] = v.y;
    tile[rr][c0 + 2] = v.z; tile[rr][c0 + 3] = v.w;
    __syncthreads();

    u16x4 hw, lw;
#pragma unroll
    for (int i = 0; i < 4; ++i) {
        float f = tile[c0 + i][rr];
        u16 hi = f32_to_bf16(f);
        hw[i] = hi;
        lw[i] = f32_to_bf16(f - bf16_to_f32(hi));
    }
    size_t o = (size_t)(n0 + rr) * DD + k0 + c0;
    *(u16x4*)&th[o] = hw;
    *(u16x4*)&tl[o] = lw;
}

// ---------------------------------------------------------------------------
// Split-cast X (query,key): f32 -> hi/lo bf16 flat buffers.
// ---------------------------------------------------------------------------
__global__ __launch_bounds__(256)
void cast_X(const float* __restrict__ query, const float* __restrict__ key,
            u16* __restrict__ Xh, u16* __restrict__ Xl)
{
    const float* src = blockIdx.y ? key : query;
    u16* dh = Xh + (size_t)blockIdx.y * NPROJ;
    u16* dl = Xl + (size_t)blockIdx.y * NPROJ;
    size_t i0 = ((size_t)blockIdx.x * 256 + threadIdx.x) * 8;
    float f[8];
    *(float4*)&f[0] = *(const float4*)(src + i0);
    *(float4*)&f[4] = *(const float4*)(src + i0 + 4);
    short8 h, l;
#pragma unroll
    for (int i = 0; i < 8; ++i) {
        u16 hi = f32_to_bf16(f[i]);
        h[i] = (short)hi;
        l[i] = (short)f32_to_bf16(f[i] - bf16_to_f32(hi));
    }
    *(short8*)&dh[i0] = h;
    *(short8*)&dl[i0] = l;
}

// ---------------------------------------------------------------------------
// Projection GEMM v2: operand-swapped MFMA (lane acc = 4 consecutive n)
// -> packed u16x4 stores. z<4: 3-term bf16x3 hi/lo out; z>=4: hi-only 1-term.
// 128x128 tile, BK=32, 256 threads (4 waves), global_load_lds staging.
// ---------------------------------------------------------------------------
__global__ __launch_bounds__(256)
void proj_gemm_gld(const u16* __restrict__ Xh, const u16* __restrict__ Xl,
                   const u16* __restrict__ WTh, const u16* __restrict__ WTl,
                   const float* __restrict__ b0, const float* __restrict__ b1,
                   const float* __restrict__ b2, const float* __restrict__ b3,
                   const float* __restrict__ b4, const float* __restrict__ b5,
                   u16* __restrict__ Ph, u16* __restrict__ Pl)
{
    __shared__ alignas(16) u16 Ash[128][32];   // unpadded: gld16 requires contiguity
    __shared__ alignas(16) u16 Asl[128][32];
    __shared__ alignas(16) u16 Bsh[128][32];
    __shared__ alignas(16) u16 Bsl[128][32];

    const int z = blockIdx.z;
    const float* bias;
    switch (z) {
        case 0: bias = b0; break; case 1: bias = b1; break; case 2: bias = b2; break;
        case 3: bias = b3; break; case 4: bias = b4; break; default: bias = b5; break;
    }
    const float scl = (z & 1) ? 1.0f : SCALEQ;
    const u16* Ah_g = Xh + (size_t)(z & 1) * NPROJ;
    const u16* Al_g = Xl + (size_t)(z & 1) * NPROJ;
    const u16* WThz = WTh + (size_t)z * WSZ;
    const u16* WTlz = WTl + (size_t)z * WSZ;
    u16* Ch = Ph + (size_t)z * NPROJ;
    u16* Cl = Pl + (size_t)z * NPROJ;
    const bool wlo = (z < 4);

    const int t = threadIdx.x;
    const int w = t >> 6, l = t & 63, quad = l >> 4, ln = l & 15;
    const int m0 = blockIdx.y * 128, n0 = blockIdx.x * 128;
    const int wm = (w & 1) * 64, wn = (w >> 1) * 64;

    const int srow = w * 16 + (l >> 2);
    const int scol = (l & 3) * 8;
    const u16* gAh = Ah_g + (size_t)(m0 + srow) * DD + scol;
    const u16* gAl = Al_g + (size_t)(m0 + srow) * DD + scol;
    const u16* gBh = WThz + (size_t)(n0 + srow) * DD + scol;
    const u16* gBl = WTlz + (size_t)(n0 + srow) * DD + scol;
    u16* lAh0 = &Ash[w * 16][0];      u16* lAh1 = &Ash[w * 16 + 64][0];
    u16* lAl0 = &Asl[w * 16][0];      u16* lAl1 = &Asl[w * 16 + 64][0];
    u16* lBh0 = &Bsh[w * 16][0];      u16* lBh1 = &Bsh[w * 16 + 64][0];
    u16* lBl0 = &Bsl[w * 16][0];      u16* lBl1 = &Bsl[w * 16 + 64][0];
    const size_t rstep = (size_t)64 * DD;

    f32x4 acc[4][4];   // acc[mt][nt]; lane holds n = wn+nt*16+quad*4+reg, m = wm+mt*16+ln
#pragma unroll
    for (int i = 0; i < 4; ++i)
#pragma unroll
        for (int jj = 0; jj < 4; ++jj) acc[i][jj] = (f32x4){0.f, 0.f, 0.f, 0.f};

    for (int k0 = 0; k0 < DD; k0 += 32) {
        gld16(gAh + k0, lAh0);  gld16(gAh + k0 + rstep, lAh1);
        gld16(gBh + k0, lBh0);  gld16(gBh + k0 + rstep, lBh1);
        if (wlo) {
            gld16(gAl + k0, lAl0);  gld16(gAl + k0 + rstep, lAl1);
            gld16(gBl + k0, lBl0);  gld16(gBl + k0 + rstep, lBl1);
        }
        __syncthreads();

        short8 afh[4], afl[4], bfh[4], bfl[4];
#pragma unroll
        for (int mt = 0; mt < 4; ++mt)
            afh[mt] = *(const short8*)&Ash[wm + mt * 16 + ln][quad * 8];
#pragma unroll
        for (int nt = 0; nt < 4; ++nt)
            bfh[nt] = *(const short8*)&Bsh[wn + nt * 16 + ln][quad * 8];
        if (wlo) {
#pragma unroll
            for (int mt = 0; mt < 4; ++mt)
                afl[mt] = *(const short8*)&Asl[wm + mt * 16 + ln][quad * 8];
#pragma unroll
            for (int nt = 0; nt < 4; ++nt)
                bfl[nt] = *(const short8*)&Bsl[wn + nt * 16 + ln][quad * 8];
        }
        // operand-swapped: first operand indexes D's row dim (= n), second = m
#pragma unroll
        for (int mt = 0; mt < 4; ++mt)
#pragma unroll
            for (int nt = 0; nt < 4; ++nt) {
                acc[mt][nt] = MFMA16(bfh[nt], afh[mt], acc[mt][nt], 0, 0, 0);
                if (wlo) {
                    acc[mt][nt] = MFMA16(bfl[nt], afh[mt], acc[mt][nt], 0, 0, 0);
                    acc[mt][nt] = MFMA16(bfh[nt], afl[mt], acc[mt][nt], 0, 0, 0);
                }
            }
        __syncthreads();
    }

    // epilogue: lane stores 4 consecutive n as u16x4
#pragma unroll
    for (int nt = 0; nt < 4; ++nt) {
        const int nb4 = n0 + wn + nt * 16 + quad * 4;
        float4 bias4 = *(const float4*)(bias + nb4);
        float bv[4] = {bias4.x, bias4.y, bias4.z, bias4.w};
#pragma unroll
        for (int mt = 0; mt < 4; ++mt) {
            const int m = m0 + wm + mt * 16 + ln;
            u16x4 hv, lv;
#pragma unroll
            for (int reg = 0; reg < 4; ++reg) {
                float c = (acc[mt][nt][reg] + bv[reg]) * scl;
                u16 hi = f32_to_bf16(c);
                hv[reg] = hi;
                lv[reg] = f32_to_bf16(c - bf16_to_f32(hi));
            }
            size_t o = (size_t)m * DD + nb4;
            *(u16x4*)&Ch[o] = hv;
            if (wlo) *(u16x4*)&Cl[o] = lv;
        }
    }
}

// ---------------------------------------------------------------------------
// Fallback projection GEMM (round-2 style, f32 A staged in-kernel).
// ---------------------------------------------------------------------------
__global__ __launch_bounds__(256)
void proj_gemm_mfma(const float* __restrict__ query, const float* __restrict__ key,
                    const u16* __restrict__ WTh, const u16* __restrict__ WTl,
                    const float* __restrict__ b0, const float* __restrict__ b1,
                    const float* __restrict__ b2, const float* __restrict__ b3,
                    const float* __restrict__ b4, const float* __restrict__ b5,
                    u16* __restrict__ Ph, u16* __restrict__ Pl)
{
    __shared__ alignas(16) u16 Ash[128][40];
    __shared__ alignas(16) u16 Asl[128][40];
    __shared__ alignas(16) u16 Bsh[128][40];
    __shared__ alignas(16) u16 Bsl[128][40];

    const int z = blockIdx.z;
    const float* X = (z & 1) ? key : query;
    const float* bias;
    switch (z) {
        case 0: bias = b0; break; case 1: bias = b1; break; case 2: bias = b2; break;
        case 3: bias = b3; break; case 4: bias = b4; break; default: bias = b5; break;
    }
    const float scl = (z & 1) ? 1.0f : SCALEQ;
    const u16* WThz = WTh + (size_t)z * WSZ;
    const u16* WTlz = WTl + (size_t)z * WSZ;
    u16* Ch = Ph + (size_t)z * NPROJ;
    u16* Cl = Pl + (size_t)z * NPROJ;
    const bool wlo = (z < 4);

    const int t = threadIdx.x;
    const int w = t >> 6, l = t & 63, quad = l >> 4, ln = l & 15;
    const int m0 = blockIdx.y * 128, n0 = blockIdx.x * 128;
    const int wm = (w & 1) * 64, wn = (w >> 1) * 64;

    const int arow = t >> 1, akoff = (t & 1) * 16;
    const int brow = t >> 1, bkoff = (t & 1) * 16;

    f32x4 acc[4][4];
#pragma unroll
    for (int i = 0; i < 4; ++i)
#pragma unroll
        for (int jj = 0; jj < 4; ++jj) acc[i][jj] = (f32x4){0.f, 0.f, 0.f, 0.f};

    for (int k0 = 0; k0 < DD; k0 += 32) {
        {
            const float* asrc = X + (size_t)(m0 + arow) * DD + k0 + akoff;
            float fa[16];
            *(float4*)&fa[0]  = *(const float4*)(asrc + 0);
            *(float4*)&fa[4]  = *(const float4*)(asrc + 4);
            *(float4*)&fa[8]  = *(const float4*)(asrc + 8);
            *(float4*)&fa[12] = *(const float4*)(asrc + 12);
            short8 h0, h1, l0, l1;
#pragma unroll
            for (int i = 0; i < 8; ++i) {
                u16 hi = f32_to_bf16(fa[i]);
                h0[i] = (short)hi;
                l0[i] = (short)f32_to_bf16(fa[i] - bf16_to_f32(hi));
                u16 hi2 = f32_to_bf16(fa[8 + i]);
                h1[i] = (short)hi2;
                l1[i] = (short)f32_to_bf16(fa[8 + i] - bf16_to_f32(hi2));
            }
            *(short8*)&Ash[arow][akoff]     = h0;
            *(short8*)&Ash[arow][akoff + 8] = h1;
            *(short8*)&Asl[arow][akoff]     = l0;
            *(short8*)&Asl[arow][akoff + 8] = l1;
        }
        {
            const u16* bhp = WThz + (size_t)(n0 + brow) * DD + k0 + bkoff;
            const u16* blp = WTlz + (size_t)(n0 + brow) * DD + k0 + bkoff;
            *(uint4*)&Bsh[brow][bkoff]     = *(const uint4*)(bhp);
            *(uint4*)&Bsh[brow][bkoff + 8] = *(const uint4*)(bhp + 8);
            *(uint4*)&Bsl[brow][bkoff]     = *(const uint4*)(blp);
            *(uint4*)&Bsl[brow][bkoff + 8] = *(const uint4*)(blp + 8);
        }
        __syncthreads();

        short8 afh[4], afl[4], bfh[4], bfl[4];
#pragma unroll
        for (int mt = 0; mt < 4; ++mt) {
            afh[mt] = *(const short8*)&Ash[wm + mt * 16 + ln][quad * 8];
            afl[mt] = *(const short8*)&Asl[wm + mt * 16 + ln][quad * 8];
        }
#pragma unroll
        for (int nt = 0; nt < 4; ++nt) {
            bfh[nt] = *(const short8*)&Bsh[wn + nt * 16 + ln][quad * 8];
            bfl[nt] = *(const short8*)&Bsl[wn + nt * 16 + ln][quad * 8];
        }
#pragma unroll
        for (int mt = 0; mt < 4; ++mt)
#pragma unroll
            for (int nt = 0; nt < 4; ++nt) {
                acc[mt][nt] = MFMA16(bfh[nt], afh[mt], acc[mt][nt], 0, 0, 0);
                acc[mt][nt] = MFMA16(bfl[nt], afh[mt], acc[mt][nt], 0, 0, 0);
                acc[mt][nt] = MFMA16(bfh[nt], afl[mt], acc[mt][nt], 0, 0, 0);
            }
        __syncthreads();
    }

#pragma unroll
    for (int nt = 0; nt < 4; ++nt) {
        const int nb4 = n0 + wn + nt * 16 + quad * 4;
        float4 bias4 = *(const float4*)(bias + nb4);
        float bv[4] = {bias4.x, bias4.y, bias4.z, bias4.w};
#pragma unroll
        for (int mt = 0; mt < 4; ++mt) {
            const int m = m0 + wm + mt * 16 + ln;
            u16x4 hv, lv;
#pragma unroll
            for (int reg = 0; reg < 4; ++reg) {
                float c = (acc[mt][nt][reg] + bv[reg]) * scl;
                u16 hi = f32_to_bf16(c);
                hv[reg] = hi;
                lv[reg] = f32_to_bf16(c - bf16_to_f32(hi));
            }
            size_t o = (size_t)m * DD + nb4;
            *(u16x4*)&Ch[o] = hv;
            if (wlo) *(u16x4*)&Cl[o] = lv;
        }
    }
}

// ---------------------------------------------------------------------------
// Attention v8 = v7 (fused L+R, 3 barriers, M-frag + span prefetch,
// in-register BCE) with the loss path DE-ATOMIZED.
// r5 evidence: 24576 same-address atomicAdds serialized GPU-wide (~8-15ns
// each, cross-XCD line ping-pong) -> attn 155->358us; same mechanism made
// r4's bce_loss 2x slow (6144 atomics). Fix: per-block partial -> plain
// store into scratch (dead WTh region); tiny loss_reduce kernel sums 3072
// floats. Zero atomics in the entire pipeline.
// ---------------------------------------------------------------------------
#define CPITCH 532
__global__ __launch_bounds__(512, 4)
void attn_mfma(const u16* __restrict__ Ph, const u16* __restrict__ Pl,
               const float* __restrict__ mask, const float* __restrict__ span,
               float* __restrict__ outp, float* __restrict__ partial)
{
    __shared__ float curbL[16][CPITCH];
    __shared__ float curbR[16][CPITCH];
    __shared__ float lred[8];

    const int t = threadIdx.x;
    const int blk = blockIdx.x;
    const int qt = blk & 31;
    const int bh = blk >> 5;
    const int b = bh / HH, h = bh % HH;
    const int w = t >> 6, l = t & 63, quad = l >> 4, ln = l & 15;
    const int r = t >> 5, j = t & 31;
    const int qrow = qt * 16 + r;
    const int bb = 33 * (j >> 1) + 16 * (j & 1);   // layout-B base (16 consecutive)
    const int cB = j * 16;                         // first column owned in layout B

    float smbr[16];

    const size_t qoff = (size_t)(b * SS + qt * 16 + ln) * DD + h * DKK + quad * 8;
    const size_t koff = (size_t)(b * SS + w * 16 + ln) * DD + h * DKK + quad * 8;

    const u16* QhL = Ph + 0 * (size_t)NPROJ;  const u16* QlL = Pl + 0 * (size_t)NPROJ;
    const u16* KhL = Ph + 1 * (size_t)NPROJ;  const u16* KlL = Pl + 1 * (size_t)NPROJ;
    const u16* QhR = Ph + 2 * (size_t)NPROJ;  const u16* QlR = Pl + 2 * (size_t)NPROJ;
    const u16* KhR = Ph + 3 * (size_t)NPROJ;  const u16* KlR = Pl + 3 * (size_t)NPROJ;
    const u16* QhM = Ph + 4 * (size_t)NPROJ;
    const u16* KhM = Ph + 5 * (size_t)NPROJ;

    // ---------------- Phase 1: L+R scores (fused, one barrier region) ------
    {
        short8 aLh0 = *(const short8*)(QhL + qoff);
        short8 aLh1 = *(const short8*)(QhL + qoff + 32);
        short8 aLl0 = *(const short8*)(QlL + qoff);
        short8 aLl1 = *(const short8*)(QlL + qoff + 32);
        short8 aRh0 = *(const short8*)(QhR + qoff);
        short8 aRh1 = *(const short8*)(QhR + qoff + 32);
        short8 aRl0 = *(const short8*)(QlR + qoff);
        short8 aRl1 = *(const short8*)(QlR + qoff + 32);
#pragma unroll
        for (int kc = 0; kc < 4; ++kc) {
            const size_t off = koff + (size_t)kc * (128 * DD);
            const int cb = kc * 128 + w * 16 + ln;
            const int ci = cb + (cb >> 5);
            {
                short8 bh0 = *(const short8*)(KhL + off);
                short8 bh1 = *(const short8*)(KhL + off + 32);
                short8 bl0 = *(const short8*)(KlL + off);
                short8 bl1 = *(const short8*)(KlL + off + 32);
                f32x4 acc = (f32x4){0.f, 0.f, 0.f, 0.f};
                acc = MFMA16(aLh0, bh0, acc, 0, 0, 0);
                acc = MFMA16(aLh1, bh1, acc, 0, 0, 0);
                acc = MFMA16(aLh0, bl0, acc, 0, 0, 0);
                acc = MFMA16(aLh1, bl1, acc, 0, 0, 0);
                acc = MFMA16(aLl0, bh0, acc, 0, 0, 0);
                acc = MFMA16(aLl1, bh1, acc, 0, 0, 0);
#pragma unroll
                for (int reg = 0; reg < 4; ++reg)
                    curbL[quad * 4 + reg][ci] = acc[reg];
            }
            {
                short8 bh0 = *(const short8*)(KhR + off);
                short8 bh1 = *(const short8*)(KhR + off + 32);
                short8 bl0 = *(const short8*)(KlR + off);
                short8 bl1 = *(const short8*)(KlR + off + 32);
                f32x4 acc = (f32x4){0.f, 0.f, 0.f, 0.f};
                acc = MFMA16(aRh0, bh0, acc, 0, 0, 0);
                acc = MFMA16(aRh1, bh1, acc, 0, 0, 0);
                acc = MFMA16(aRh0, bl0, acc, 0, 0, 0);
                acc = MFMA16(aRh1, bl1, acc, 0, 0, 0);
                acc = MFMA16(aRl0, bh0, acc, 0, 0, 0);
                acc = MFMA16(aRl1, bh1, acc, 0, 0, 0);
#pragma unroll
                for (int reg = 0; reg < 4; ++reg)
                    curbR[quad * 4 + reg][ci] = acc[reg];
            }
        }
    }
    __syncthreads();    // barrier 1: L+R scores visible

    // Prefetch stage M fragments NOW -- they fly under the softmax VALU.
    short8 aMh0 = *(const short8*)(QhM + qoff);
    short8 aMh1 = *(const short8*)(QhM + qoff + 32);
    short8 km0[4], km1[4];
#pragma unroll
    for (int kc = 0; kc < 4; ++kc) {
        const size_t off = koff + (size_t)kc * (128 * DD);
        km0[kc] = *(const short8*)(KhM + off);
        km1[kc] = *(const short8*)(KhM + off + 32);
    }

    // ---------------- Softmax L (layout B, r2-verified) ----------------
    {
        float e[16];
        float mx = -3.0e38f;
#pragma unroll
        for (int u = 0; u < 16; ++u) {
            float v = curbL[r][bb + u];
            e[u] = v;
            if (cB + u <= qrow && v > mx) mx = v;
        }
#pragma unroll
        for (int off = 16; off >= 1; off >>= 1) mx = fmaxf(mx, __shfl_xor(mx, off));
        float s = 0.0f;
#pragma unroll
        for (int u = 0; u < 16; ++u) {
            float ev = (cB + u <= qrow) ? __expf(e[u] - mx) : 0.0f;
            s += ev;
            e[u] = s;
        }
        float incl = s;
#pragma unroll
        for (int off = 1; off < 32; off <<= 1) {
            float ww = __shfl_up(incl, off, 32);
            if (j >= off) incl += ww;
        }
        float offset = incl - s;
        float inv = 1.0f / __shfl(incl, 31, 32);
#pragma unroll
        for (int u = 0; u < 16; ++u) smbr[u] = (offset + e[u]) * inv;
    }

    // ---------------- Softmax R (layout B, r2-verified) ----------------
    {
        float e[16];
        float mx = -3.0e38f;
#pragma unroll
        for (int u = 0; u < 16; ++u) {
            float v = curbR[r][bb + u];
            e[u] = v;
            if (cB + u >= qrow && v > mx) mx = v;
        }
#pragma unroll
        for (int off = 16; off >= 1; off >>= 1) mx = fmaxf(mx, __shfl_xor(mx, off));
        float s = 0.0f;
#pragma unroll
        for (int u = 15; u >= 0; --u) {
            float ev = (cB + u >= qrow) ? __expf(e[u] - mx) : 0.0f;
            s += ev;
            e[u] = s;
        }
        float incl = s;
#pragma unroll
        for (int off = 1; off < 32; off <<= 1) {
            float ww = __shfl_down(incl, off, 32);
            if (j + off < 32) incl += ww;
        }
        float offset = incl - s;
        float inv = 1.0f / __shfl(incl, 0, 32);
#pragma unroll
        for (int u = 0; u < 16; ++u) smbr[u] *= (offset + e[u]) * inv;

        // transpose smbr B -> A through curbL (each thread overwrites only
        // positions it alone read in softmax L -> no pre-barrier)
#pragma unroll
        for (int u = 0; u < 16; ++u) curbL[r][bb + u] = smbr[u];
    }
    __syncthreads();    // barrier 2: transpose visible; curbR free for M

    // span prefetch: issued NOW so HBM latency hides under phase-2 MFMA +
    // softmax M; consumed only in the BCE tail.
    const float* sprow = span + (((size_t)(h * BB + b) * SS + qrow)) * SS;
    float sp[16];
#pragma unroll
    for (int u = 0; u < 16; ++u) sp[u] = sprow[u * 32 + j];

    // smbr in layout A
#pragma unroll
    for (int u = 0; u < 16; ++u) smbr[u] = curbL[r][u * 33 + j];

    // ---------------- Phase 2: M scores (prefetched frags) ----------------
#pragma unroll
    for (int kc = 0; kc < 4; ++kc) {
        const int cb = kc * 128 + w * 16 + ln;
        const int ci = cb + (cb >> 5);
        f32x4 acc = (f32x4){0.f, 0.f, 0.f, 0.f};
        acc = MFMA16(aMh0, km0[kc], acc, 0, 0, 0);
        acc = MFMA16(aMh1, km1[kc], acc, 0, 0, 0);
#pragma unroll
        for (int reg = 0; reg < 4; ++reg)
            curbR[quad * 4 + reg][ci] = acc[reg];
    }
    __syncthreads();    // barrier 3: M scores visible

    // ---------------- Softmax M + p store + in-register BCE ---------------
    {
        float mv  = mask[b * SS + qrow];
        float rmq = (mv == -10000.0f) ? 1.0e9f : mv;
        float vb[16];
        float mx = -3.0e38f;
#pragma unroll
        for (int u = 0; u < 16; ++u) {
            int c = u * 32 + j;
            float mk  = mask[b * SS + c];
            float rmk = (mk == -10000.0f) ? 1.0e9f : mk;
            float v = (curbR[r][u * 33 + j] - rmq - rmk) * smbr[u];
            vb[u] = v;
            mx = fmaxf(mx, v);
        }
#pragma unroll
        for (int off = 16; off >= 1; off >>= 1) mx = fmaxf(mx, __shfl_xor(mx, off));
        float sum = 0.0f;
#pragma unroll
        for (int u = 0; u < 16; ++u) {
            float ev = __expf(vb[u] - mx);
            vb[u] = ev; sum += ev;
        }
#pragma unroll
        for (int off = 16; off >= 1; off >>= 1) sum += __shfl_xor(sum, off);
        float inv = 1.0f / sum;

        float* orow = outp + (((size_t)(b * HH + h) * SS + qrow)) * SS;
        float lsum = 0.0f;
#pragma unroll
        for (int u = 0; u < 16; ++u) {
            float p = vb[u] * inv;
            orow[u * 32 + j] = p;
            lsum += __logf(1.0f + __expf(-p)) + (1.0f - sp[u]) * p;
        }
        // wave reduce -> LDS -> one plain store per block (NO atomics)
#pragma unroll
        for (int off = 32; off >= 1; off >>= 1) lsum += __shfl_xor(lsum, off);
        if (l == 0) lred[w] = lsum;
    }
    __syncthreads();
    if (t == 0) {
        float tot = lred[0] + lred[1] + lred[2] + lred[3]
                  + lred[4] + lred[5] + lred[6] + lred[7];
        partial[blk] = tot;
    }
}

// ---------------------------------------------------------------------------
// Final loss reduction: 3072 block partials -> scalar. One block, no atomics.
// ---------------------------------------------------------------------------
__global__ __launch_bounds__(1024)
void loss_reduce(const float* __restrict__ part, float* __restrict__ lossp)
{
    __shared__ float lr[16];
    const int t = threadIdx.x;
    float s = part[t] + part[t + 1024] + part[t + 2048];
#pragma unroll
    for (int off = 32; off >= 1; off >>= 1) s += __shfl_xor(s, off);
    if ((t & 63) == 0) lr[t >> 6] = s;
    __syncthreads();
    if (t == 0) {
        float tot = 0.0f;
#pragma unroll
        for (int i = 0; i < 16; ++i) tot += lr[i];
        *lossp = tot * (float)(1.0 / 25165824.0);
    }
}

extern "C" void kernel_launch(void* const* d_in, const int* in_sizes, int n_in,
                              void* d_out, int out_size, void* d_ws, size_t ws_size,
                              hipStream_t stream)
{
    const float* query = (const float*)d_in[0];
    const float* key_t = (const float*)d_in[1];
    const float* mask  = (const float*)d_in[2];
    const float* span  = (const float*)d_in[3];
    const float* Wql = (const float*)d_in[4];  const float* bql = (const float*)d_in[5];
    const float* Wkl = (const float*)d_in[6];  const float* bkl = (const float*)d_in[7];
    const float* Wqr = (const float*)d_in[8];  const float* bqr = (const float*)d_in[9];
    const float* Wkr = (const float*)d_in[10]; const float* bkr = (const float*)d_in[11];
    const float* Wq  = (const float*)d_in[12]; const float* bq  = (const float*)d_in[13];
    const float* Wk  = (const float*)d_in[14]; const float* bk  = (const float*)d_in[15];

    float* out = (float*)d_out;
    float* lossp = out + NELEM;

    // ws layout (u16): WTh[6W] WTl[6W] Ph[6P] Pl[4P] | Xh[2P] Xl[2P] (big-ws only)
    u16* ws16 = (u16*)d_ws;
    u16* WTh = ws16;
    u16* WTl = WTh + (size_t)6 * WSZ;
    u16* Ph  = WTl + (size_t)6 * WSZ;
    u16* Pl  = Ph + (size_t)6 * NPROJ;
    u16* Xh  = Pl + (size_t)4 * NPROJ;
    u16* Xl  = Xh + (size_t)2 * NPROJ;
    const size_t need_big = ((size_t)12 * WSZ + (size_t)14 * NPROJ) * 2;  // 102.24 MB
    const bool bigws = ws_size >= need_big;

    // loss partials: reuse the WTh region (dead after proj; attn/reduce only)
    float* partial = (float*)WTh;

    cast_wT<<<dim3(24, 24, 6), dim3(256), 0, stream>>>(
        Wql, Wkl, Wqr, Wkr, Wq, Wk, WTh, WTl, lossp);

    if (bigws) {
        cast_X<<<dim3(1536, 2), dim3(256), 0, stream>>>(query, key_t, Xh, Xl);
        proj_gemm_gld<<<dim3(DD / 128, NTOK / 128, 6), dim3(256), 0, stream>>>(
            Xh, Xl, WTh, WTl, bql, bkl, bqr, bkr, bq, bk, Ph, Pl);
    } else {
        proj_gemm_mfma<<<dim3(DD / 128, NTOK / 128, 6), dim3(256), 0, stream>>>(
            query, key_t, WTh, WTl, bql, bkl, bqr, bkr, bq, bk, Ph, Pl);
    }

    attn_mfma<<<dim3(96 * 32), dim3(512), 0, stream>>>(
        Ph, Pl, mask, span, out, partial);

    loss_reduce<<<dim3(1), dim3(1024), 0, stream>>>(partial, lossp);
}